// Round 3
// baseline (904.184 us; speedup 1.0000x reference)
//
#include <hip/hip_runtime.h>
#include <cstdint>
#include <cstddef>

#define B_ 8
#define C_ 64
#define N_ 4096
#define O_ 64
#define ROWS_ (B_*N_)          // 32768
#define SPLIT_ 4
#define MSPAN_ (N_/SPLIT_)     // 1024
#define CAP_ 16
#define BUFSTRIDE_ 17          // u64 stride: lane i -> bank 2i mod 32 (2-way, free)

typedef unsigned long long u64;
typedef unsigned int u32;
typedef unsigned short u16;

// ---- workspace layout (bytes) ----
// xf   [ROWS][64] f32 : 0         (8 MB)
// sq   [ROWS]     f32 : 8388608   (128 KB)
// kd   [ROWS][64] u32 : 8519680   (8 MB)
// ki   [ROWS][64] u16 : 16908288  (4 MB)
// knn  [ROWS][16] i32 : 21102592  (2 MB)
// -- after k_merge kd/ki dead; after k_aggr knn dead --
// h    [ROWS][64] f32 : 8519680   (8 MB, aliases kd)
// h1   [ROWS][64] f32 : 16908288  (8 MB, aliases ki+knn; written after both dead)
// bn   sums/params    : 25296896  (1 KB, fresh — zeroed in k_transpose)
#define OFF_XF   0
#define OFF_SQ   8388608
#define OFF_KD   8519680
#define OFF_KI   16908288
#define OFF_IDX  21102592
#define OFF_H    8519680
#define OFF_H1   16908288
#define OFF_BN   25296896

__device__ __forceinline__ void insert16(u64 kv[16], u64 key) {
  if (key < kv[15]) {
#pragma unroll
    for (int j = 15; j > 0; --j) {
      u64 a = kv[j-1], b = kv[j];
      kv[j] = (key < a) ? a : ((key < b) ? key : b);
    }
    kv[0] = (key < kv[0]) ? key : kv[0];
  }
}

// ---------------- K1: transpose [B,C,N] -> xf[B,N,C], plus sq; zero bn ----------------
__global__ __launch_bounds__(256) void k_transpose(const float* __restrict__ x,
                                                   float* __restrict__ xf,
                                                   float* __restrict__ sq,
                                                   float* __restrict__ bn_acc) {
  __shared__ float lds[64 * 65];
  const int b  = blockIdx.x >> 6;          // 8 batches
  const int n0 = (blockIdx.x & 63) << 6;   // 64 n-tiles of 64
  const int tid = threadIdx.x;
  if (blockIdx.x == 0 && tid < 128) bn_acc[tid] = 0.f;
  const float* xb = x + (size_t)b * C_ * N_;
  {
    const int nn = tid & 63;
    const int c0 = tid >> 6;
#pragma unroll
    for (int i = 0; i < 16; ++i) {
      int c = c0 + i * 4;
      lds[c * 65 + nn] = xb[(size_t)c * N_ + n0 + nn];   // coalesced over n
    }
  }
  __syncthreads();
  {
    const int cc  = tid & 63;
    const int nn0 = tid >> 6;
#pragma unroll
    for (int i = 0; i < 16; ++i) {
      int nn = nn0 + i * 4;
      xf[((size_t)(b * N_ + n0 + nn)) * 64 + cc] = lds[cc * 65 + nn]; // coalesced over c
    }
  }
  if (tid < 64) {
    float s = 0.f;
#pragma unroll
    for (int c = 0; c < 64; ++c) { float v = lds[c * 65 + tid]; s += v * v; }
    sq[b * N_ + n0 + tid] = s;
  }
}

// ---------------- K2: fused distance + partial top-16 ----------------
// grid: 8 b x 16 nblk x 4 split = 512 blocks of 256 threads; thread owns one row.
__global__ __launch_bounds__(256)
__attribute__((amdgpu_waves_per_eu(2)))
void k_knn(const float* __restrict__ xf,
           const float* __restrict__ sq,
           u32* __restrict__ kd,
           u16* __restrict__ ki) {
  __shared__ u64 buf[256 * BUFSTRIDE_];    // padded per-lane candidate buffers (34 KB)
  const int bx    = blockIdx.x;
  const int split = bx & (SPLIT_ - 1);
  const int nblk  = (bx >> 2) & 15;
  const int b     = bx >> 6;
  const int tid   = threadIdx.x;
  const int n     = nblk * 256 + tid;
  const int r     = b * N_ + n;
  const float* __restrict__ xfb = xf + (size_t)b * N_ * 64;

  // own-row features; inline-asm pin forbids rematerialization of the loads
  float xr[64];
  {
    const float4* xr4 = (const float4*)(xfb + (size_t)n * 64);
#pragma unroll
    for (int j = 0; j < 16; ++j) {
      float4 v = xr4[j];
      xr[4*j+0] = v.x; xr[4*j+1] = v.y; xr[4*j+2] = v.z; xr[4*j+3] = v.w;
    }
  }
#pragma unroll
  for (int j = 0; j < 64; ++j) asm volatile("" : "+v"(xr[j]));

  const float sqn = sq[r];
  const float* __restrict__ sqb = sq + b * N_;

  u64 kv[16];
#pragma unroll
  for (int j = 0; j < 16; ++j) kv[j] = ~0ULL;
  u64 thresh = ~0ULL;
  int cnt = 0;
  u64* mybuf = buf + tid * BUFSTRIDE_;

  const int mbase = split * MSPAN_;
  for (int m = 0; m < MSPAN_; ++m) {
    const float4* mr = (const float4*)(xfb + (size_t)(mbase + m) * 64); // wave-uniform
    float a0 = 0.f, a1 = 0.f, a2 = 0.f, a3 = 0.f;
    {
      float4 v0 = mr[0],  v1 = mr[1],  v2 = mr[2],  v3 = mr[3];
      a0 += v0.x*xr[0]  + v0.y*xr[1]  + v0.z*xr[2]  + v0.w*xr[3];
      a1 += v1.x*xr[4]  + v1.y*xr[5]  + v1.z*xr[6]  + v1.w*xr[7];
      a2 += v2.x*xr[8]  + v2.y*xr[9]  + v2.z*xr[10] + v2.w*xr[11];
      a3 += v3.x*xr[12] + v3.y*xr[13] + v3.z*xr[14] + v3.w*xr[15];
    }
    {
      float4 v0 = mr[4],  v1 = mr[5],  v2 = mr[6],  v3 = mr[7];
      a0 += v0.x*xr[16] + v0.y*xr[17] + v0.z*xr[18] + v0.w*xr[19];
      a1 += v1.x*xr[20] + v1.y*xr[21] + v1.z*xr[22] + v1.w*xr[23];
      a2 += v2.x*xr[24] + v2.y*xr[25] + v2.z*xr[26] + v2.w*xr[27];
      a3 += v3.x*xr[28] + v3.y*xr[29] + v3.z*xr[30] + v3.w*xr[31];
    }
    {
      float4 v0 = mr[8],  v1 = mr[9],  v2 = mr[10], v3 = mr[11];
      a0 += v0.x*xr[32] + v0.y*xr[33] + v0.z*xr[34] + v0.w*xr[35];
      a1 += v1.x*xr[36] + v1.y*xr[37] + v1.z*xr[38] + v1.w*xr[39];
      a2 += v2.x*xr[40] + v2.y*xr[41] + v2.z*xr[42] + v2.w*xr[43];
      a3 += v3.x*xr[44] + v3.y*xr[45] + v3.z*xr[46] + v3.w*xr[47];
    }
    {
      float4 v0 = mr[12], v1 = mr[13], v2 = mr[14], v3 = mr[15];
      a0 += v0.x*xr[48] + v0.y*xr[49] + v0.z*xr[50] + v0.w*xr[51];
      a1 += v1.x*xr[52] + v1.y*xr[53] + v1.z*xr[54] + v1.w*xr[55];
      a2 += v2.x*xr[56] + v2.y*xr[57] + v2.z*xr[58] + v2.w*xr[59];
      a3 += v3.x*xr[60] + v3.y*xr[61] + v3.z*xr[62] + v3.w*xr[63];
    }
    float d = sqn + sqb[mbase + m] - 2.f * ((a0 + a1) + (a2 + a3));
    // orderable key: sign-flip float bits; idx in low bits => (dist, idx) lexicographic
    u32 u = __float_as_uint(d);
    u ^= (u & 0x80000000u) ? 0xFFFFFFFFu : 0x80000000u;
    u64 key = ((u64)u << 32) | (u32)(mbase + m);

    bool push = key < thresh;
    if (push) { mybuf[cnt] = key; cnt++; }
    if (__any(cnt == CAP_)) {              // batch-drain
      for (int i = 0; i < cnt; ++i) insert16(kv, mybuf[i]);
      cnt = 0;
      thresh = kv[15];
    }
  }
  for (int i = 0; i < cnt; ++i) insert16(kv, mybuf[i]);

  u32* dp = kd + ((size_t)r * SPLIT_ + split) * 16;
  u16* ip = ki + ((size_t)r * SPLIT_ + split) * 16;
#pragma unroll
  for (int j = 0; j < 16; ++j) {
    dp[j] = (u32)(kv[j] >> 32);
    ip[j] = (u16)(kv[j] & 0xFFFFu);
  }
}

// ---------------- K3: merge 4 partial top-16 -> final 16 indices ----------------
__global__ __launch_bounds__(256) void k_merge(const u32* __restrict__ kd,
                                               const u16* __restrict__ ki,
                                               int* __restrict__ knn) {
  int r = blockIdx.x * 256 + threadIdx.x;
  u64 kv[16];
#pragma unroll
  for (int j = 0; j < 16; ++j) kv[j] = ~0ULL;
  const u32* dp = kd + (size_t)r * (SPLIT_ * 16);
  const u16* ip = ki + (size_t)r * (SPLIT_ * 16);
  for (int i = 0; i < SPLIT_ * 16; ++i) {
    u64 key = ((u64)dp[i] << 32) | ip[i];
    insert16(kv, key);
  }
#pragma unroll
  for (int j = 0; j < 16; ++j) knn[r * 16 + j] = (int)(kv[j] & 0xFFFFu);
}

// ---------------- K4: GIN aggregation: h = (1+eps)*xf + sum_k xf[idx] ----------------
__global__ __launch_bounds__(256) void k_aggr(const float* __restrict__ xf,
                                              const int* __restrict__ knn,
                                              const float* __restrict__ eps_gin,
                                              float* __restrict__ h) {
  const int tid = threadIdx.x;
  const int r = blockIdx.x * 4 + (tid >> 6);   // wave per row
  const int c = tid & 63;
  const int b = r >> 12;
  const float* xfb = xf + (size_t)b * N_ * 64;
  const float eps = eps_gin[0];
  float v = (1.f + eps) * xf[(size_t)r * 64 + c];
  const int* kn = knn + r * 16;
#pragma unroll
  for (int j = 0; j < 16; ++j) {
    int m = kn[j];                              // wave-uniform scalar load
    v += xfb[(size_t)m * 64 + c];               // coalesced 256B row read
  }
  h[(size_t)r * 64 + c] = v;
}

// ---------------- K5: h1 = h @ w1 + b1, plus BN partial sums ----------------
__global__ __launch_bounds__(256) void k_gemm1(const float* __restrict__ h,
                                               const float* __restrict__ w1,
                                               const float* __restrict__ b1,
                                               float* __restrict__ h1,
                                               float* __restrict__ bn_acc) {
  __shared__ float w[64 * 64];
  __shared__ float rs[4][64], rs2[4][64];
  const int tid = threadIdx.x;
#pragma unroll
  for (int i = 0; i < 16; ++i) w[tid + i * 256] = w1[tid + i * 256];
  __syncthreads();
  const int o = tid & 63;
  const int q = tid >> 6;
  const int r0 = blockIdx.x * 64;
  const float bias = b1[o];
  float s = 0.f, s2 = 0.f;
#pragma unroll
  for (int i = 0; i < 16; ++i) {
    int row = r0 + q + i * 4;                   // wave-uniform row
    const float* hr = h + (size_t)row * 64;
    float acc = bias;
#pragma unroll
    for (int c = 0; c < 64; ++c) acc += hr[c] * w[c * 64 + o];
    h1[(size_t)row * 64 + o] = acc;
    s += acc; s2 += acc * acc;
  }
  rs[q][o] = s; rs2[q][o] = s2;
  __syncthreads();
  if (tid < 64) {
    float ts  = rs[0][tid] + rs[1][tid] + rs[2][tid] + rs[3][tid];
    float ts2 = rs2[0][tid] + rs2[1][tid] + rs2[2][tid] + rs2[3][tid];
    atomicAdd(&bn_acc[tid], ts);
    atomicAdd(&bn_acc[64 + tid], ts2);
  }
}

// ---------------- K6: finalize BN -> per-channel scale/shift ----------------
__global__ void k_bnfin(const float* __restrict__ bn_acc,
                        const float* __restrict__ gamma,
                        const float* __restrict__ beta,
                        float* __restrict__ bn_par) {
  int o = threadIdx.x;   // 64 threads
  const float inv = 1.f / (float)ROWS_;
  float mean = bn_acc[o] * inv;
  float var  = bn_acc[64 + o] * inv - mean * mean;
  float sc = gamma[o] * rsqrtf(var + 1e-5f);
  bn_par[o] = sc;
  bn_par[64 + o] = beta[o] - mean * sc;
}

// ---------------- K7: BN apply + GELU(erf) + GEMM2 + transposed store ----------------
__global__ __launch_bounds__(256) void k_final(const float* __restrict__ h1,
                                               const float* __restrict__ bn_par,
                                               const float* __restrict__ w2,
                                               const float* __restrict__ b2,
                                               float* __restrict__ out) {
  __shared__ float w[64 * 64];
  __shared__ float hg[64 * 65];                 // padded: kills stride-64 conflicts
  const int tid = threadIdx.x;
#pragma unroll
  for (int i = 0; i < 16; ++i) w[tid + i * 256] = w2[tid + i * 256];
  const int r0 = blockIdx.x * 64;
  const int b  = r0 >> 12;
  const int n0 = r0 & (N_ - 1);
  const int o = tid & 63;
  const int q = tid >> 6;
  const float sc = bn_par[o], sh = bn_par[64 + o];
#pragma unroll
  for (int i = 0; i < 16; ++i) {
    int rl = q + i * 4;
    float v = h1[(size_t)(r0 + rl) * 64 + o] * sc + sh;
    float g = 0.5f * v * (1.f + erff(v * 0.70710678118654752f));
    hg[rl * 65 + o] = g;
  }
  __syncthreads();
  const int nl = tid & 63;
#pragma unroll
  for (int i = 0; i < 16; ++i) {
    int o2 = q + i * 4;                         // wave-uniform
    float acc = b2[o2];
#pragma unroll
    for (int oo = 0; oo < 64; ++oo) acc += hg[nl * 65 + oo] * w[oo * 64 + o2];
    out[((size_t)(b * 64 + o2)) * N_ + n0 + nl] = acc;  // coalesced over n
  }
}

extern "C" void kernel_launch(void* const* d_in, const int* in_sizes, int n_in,
                              void* d_out, int out_size, void* d_ws, size_t ws_size,
                              hipStream_t stream) {
  const float* x     = (const float*)d_in[0];
  const float* w1    = (const float*)d_in[1];
  const float* b1    = (const float*)d_in[2];
  const float* gamma = (const float*)d_in[3];
  const float* beta  = (const float*)d_in[4];
  const float* w2    = (const float*)d_in[5];
  const float* b2    = (const float*)d_in[6];
  const float* eps_g = (const float*)d_in[7];
  float* out = (float*)d_out;

  char* ws = (char*)d_ws;
  float* xf   = (float*)(ws + OFF_XF);
  float* sq   = (float*)(ws + OFF_SQ);
  u32*   kd   = (u32*)  (ws + OFF_KD);
  u16*   ki   = (u16*)  (ws + OFF_KI);
  int*   knn  = (int*)  (ws + OFF_IDX);
  float* h    = (float*)(ws + OFF_H);     // aliases kd (dead after merge)
  float* h1   = (float*)(ws + OFF_H1);    // aliases ki+knn (dead after aggr)
  float* bn_acc = (float*)(ws + OFF_BN);
  float* bn_par = (float*)(ws + OFF_BN + 512);

  k_transpose<<<512, 256, 0, stream>>>(x, xf, sq, bn_acc);
  k_knn<<<512, 256, 0, stream>>>(xf, sq, kd, ki);
  k_merge<<<ROWS_ / 256, 256, 0, stream>>>(kd, ki, knn);
  k_aggr<<<ROWS_ / 4, 256, 0, stream>>>(xf, knn, eps_g, h);
  k_gemm1<<<ROWS_ / 64, 256, 0, stream>>>(h, w1, b1, h1, bn_acc);
  k_bnfin<<<1, 64, 0, stream>>>(bn_acc, gamma, beta, bn_par);
  k_final<<<ROWS_ / 64, 256, 0, stream>>>(h1, bn_par, w2, b2, out);
}

// Round 4
// 902.984 us; speedup vs baseline: 1.0013x; 1.0013x over previous
//
#include <hip/hip_runtime.h>
#include <cstdint>
#include <cstddef>

#define B_ 8
#define C_ 64
#define N_ 4096
#define O_ 64
#define ROWS_ (B_*N_)          // 32768
#define SPLIT_ 4
#define MSPAN_ (N_/SPLIT_)     // 1024
#define CAP_ 16
#define BUFSTRIDE_ 17          // u64 stride: lane i -> bank 2i mod 32 (2-way, free)

typedef unsigned long long u64;
typedef unsigned int u32;
typedef unsigned short u16;

// ---- workspace layout (bytes) ----
// xf   [ROWS][64] f32 : 0         (8 MB)
// sq   [ROWS]     f32 : 8388608   (128 KB)
// kd   [ROWS][64] u32 : 8519680   (8 MB)
// ki   [ROWS][64] u16 : 16908288  (4 MB)
// knn  [ROWS][16] i32 : 21102592  (2 MB)
// -- after k_merge kd/ki dead; after k_aggr knn dead --
// h    [ROWS][64] f32 : 8519680   (8 MB, aliases kd)
// h1   [ROWS][64] f32 : 16908288  (8 MB, aliases ki+knn; written after both dead)
// bn   sums/params    : 25296896  (1 KB, fresh — zeroed in k_transpose)
#define OFF_XF   0
#define OFF_SQ   8388608
#define OFF_KD   8519680
#define OFF_KI   16908288
#define OFF_IDX  21102592
#define OFF_H    8519680
#define OFF_H1   16908288
#define OFF_BN   25296896

__device__ __forceinline__ void insert16(u64 kv[16], u64 key) {
  if (key < kv[15]) {
#pragma unroll
    for (int j = 15; j > 0; --j) {
      u64 a = kv[j-1], b = kv[j];
      kv[j] = (key < a) ? a : ((key < b) ? key : b);
    }
    kv[0] = (key < kv[0]) ? key : kv[0];
  }
}

// ---------------- K1: transpose [B,C,N] -> xf[B,N,C], plus sq; zero bn ----------------
__global__ __launch_bounds__(256) void k_transpose(const float* __restrict__ x,
                                                   float* __restrict__ xf,
                                                   float* __restrict__ sq,
                                                   float* __restrict__ bn_acc) {
  __shared__ float lds[64 * 65];
  const int b  = blockIdx.x >> 6;          // 8 batches
  const int n0 = (blockIdx.x & 63) << 6;   // 64 n-tiles of 64
  const int tid = threadIdx.x;
  if (blockIdx.x == 0 && tid < 128) bn_acc[tid] = 0.f;
  const float* xb = x + (size_t)b * C_ * N_;
  {
    const int nn = tid & 63;
    const int c0 = tid >> 6;
#pragma unroll
    for (int i = 0; i < 16; ++i) {
      int c = c0 + i * 4;
      lds[c * 65 + nn] = xb[(size_t)c * N_ + n0 + nn];   // coalesced over n
    }
  }
  __syncthreads();
  {
    const int cc  = tid & 63;
    const int nn0 = tid >> 6;
#pragma unroll
    for (int i = 0; i < 16; ++i) {
      int nn = nn0 + i * 4;
      xf[((size_t)(b * N_ + n0 + nn)) * 64 + cc] = lds[cc * 65 + nn]; // coalesced over c
    }
  }
  if (tid < 64) {
    float s = 0.f;
#pragma unroll
    for (int c = 0; c < 64; ++c) { float v = lds[c * 65 + tid]; s += v * v; }
    sq[b * N_ + n0 + tid] = s;
  }
}

// ---------------- K2: fused distance + partial top-16 ----------------
// grid: 8 b x 16 nblk x 4 split = 512 blocks of 256 threads; thread owns one row.
// __launch_bounds__(256, 2): min 2 waves/EU -> 256-VGPR budget so the 64
// pinned xr values stay RESIDENT (r2: budget 128 -> remat from L1; r3:
// default target -> spill to scratch. Both ~700 us. Budget is the knob.)
__global__ __launch_bounds__(256, 2)
void k_knn(const float* __restrict__ xf,
           const float* __restrict__ sq,
           u32* __restrict__ kd,
           u16* __restrict__ ki) {
  __shared__ u64 buf[256 * BUFSTRIDE_];    // padded per-lane candidate buffers (34 KB)
  const int bx    = blockIdx.x;
  const int split = bx & (SPLIT_ - 1);
  const int nblk  = (bx >> 2) & 15;
  const int b     = bx >> 6;
  const int tid   = threadIdx.x;
  const int n     = nblk * 256 + tid;
  const int r     = b * N_ + n;
  const float* __restrict__ xfb = xf + (size_t)b * N_ * 64;

  // own-row features; inline-asm pin forbids rematerialization of the loads
  float xr[64];
  {
    const float4* xr4 = (const float4*)(xfb + (size_t)n * 64);
#pragma unroll
    for (int j = 0; j < 16; ++j) {
      float4 v = xr4[j];
      xr[4*j+0] = v.x; xr[4*j+1] = v.y; xr[4*j+2] = v.z; xr[4*j+3] = v.w;
    }
  }
#pragma unroll
  for (int j = 0; j < 64; ++j) asm volatile("" : "+v"(xr[j]));

  const float sqn = sq[r];
  const float* __restrict__ sqb = sq + b * N_;

  u64 kv[16];
#pragma unroll
  for (int j = 0; j < 16; ++j) kv[j] = ~0ULL;
  u64 thresh = ~0ULL;
  int cnt = 0;
  u64* mybuf = buf + tid * BUFSTRIDE_;

  const int mbase = split * MSPAN_;
  for (int m = 0; m < MSPAN_; ++m) {
    const float4* mr = (const float4*)(xfb + (size_t)(mbase + m) * 64); // wave-uniform
    float a0 = 0.f, a1 = 0.f, a2 = 0.f, a3 = 0.f;
    {
      float4 v0 = mr[0],  v1 = mr[1],  v2 = mr[2],  v3 = mr[3];
      a0 += v0.x*xr[0]  + v0.y*xr[1]  + v0.z*xr[2]  + v0.w*xr[3];
      a1 += v1.x*xr[4]  + v1.y*xr[5]  + v1.z*xr[6]  + v1.w*xr[7];
      a2 += v2.x*xr[8]  + v2.y*xr[9]  + v2.z*xr[10] + v2.w*xr[11];
      a3 += v3.x*xr[12] + v3.y*xr[13] + v3.z*xr[14] + v3.w*xr[15];
    }
    {
      float4 v0 = mr[4],  v1 = mr[5],  v2 = mr[6],  v3 = mr[7];
      a0 += v0.x*xr[16] + v0.y*xr[17] + v0.z*xr[18] + v0.w*xr[19];
      a1 += v1.x*xr[20] + v1.y*xr[21] + v1.z*xr[22] + v1.w*xr[23];
      a2 += v2.x*xr[24] + v2.y*xr[25] + v2.z*xr[26] + v2.w*xr[27];
      a3 += v3.x*xr[28] + v3.y*xr[29] + v3.z*xr[30] + v3.w*xr[31];
    }
    {
      float4 v0 = mr[8],  v1 = mr[9],  v2 = mr[10], v3 = mr[11];
      a0 += v0.x*xr[32] + v0.y*xr[33] + v0.z*xr[34] + v0.w*xr[35];
      a1 += v1.x*xr[36] + v1.y*xr[37] + v1.z*xr[38] + v1.w*xr[39];
      a2 += v2.x*xr[40] + v2.y*xr[41] + v2.z*xr[42] + v2.w*xr[43];
      a3 += v3.x*xr[44] + v3.y*xr[45] + v3.z*xr[46] + v3.w*xr[47];
    }
    {
      float4 v0 = mr[12], v1 = mr[13], v2 = mr[14], v3 = mr[15];
      a0 += v0.x*xr[48] + v0.y*xr[49] + v0.z*xr[50] + v0.w*xr[51];
      a1 += v1.x*xr[52] + v1.y*xr[53] + v1.z*xr[54] + v1.w*xr[55];
      a2 += v2.x*xr[56] + v2.y*xr[57] + v2.z*xr[58] + v2.w*xr[59];
      a3 += v3.x*xr[60] + v3.y*xr[61] + v3.z*xr[62] + v3.w*xr[63];
    }
    float d = sqn + sqb[mbase + m] - 2.f * ((a0 + a1) + (a2 + a3));
    // orderable key: sign-flip float bits; idx in low bits => (dist, idx) lexicographic
    u32 u = __float_as_uint(d);
    u ^= (u & 0x80000000u) ? 0xFFFFFFFFu : 0x80000000u;
    u64 key = ((u64)u << 32) | (u32)(mbase + m);

    bool push = key < thresh;
    if (push) { mybuf[cnt] = key; cnt++; }
    if (__any(cnt == CAP_)) {              // batch-drain
      for (int i = 0; i < cnt; ++i) insert16(kv, mybuf[i]);
      cnt = 0;
      thresh = kv[15];
    }
  }
  for (int i = 0; i < cnt; ++i) insert16(kv, mybuf[i]);

  u32* dp = kd + ((size_t)r * SPLIT_ + split) * 16;
  u16* ip = ki + ((size_t)r * SPLIT_ + split) * 16;
#pragma unroll
  for (int j = 0; j < 16; ++j) {
    dp[j] = (u32)(kv[j] >> 32);
    ip[j] = (u16)(kv[j] & 0xFFFFu);
  }
}

// ---------------- K3: merge 4 partial top-16 -> final 16 indices ----------------
__global__ __launch_bounds__(256) void k_merge(const u32* __restrict__ kd,
                                               const u16* __restrict__ ki,
                                               int* __restrict__ knn) {
  int r = blockIdx.x * 256 + threadIdx.x;
  u64 kv[16];
#pragma unroll
  for (int j = 0; j < 16; ++j) kv[j] = ~0ULL;
  const u32* dp = kd + (size_t)r * (SPLIT_ * 16);
  const u16* ip = ki + (size_t)r * (SPLIT_ * 16);
  for (int i = 0; i < SPLIT_ * 16; ++i) {
    u64 key = ((u64)dp[i] << 32) | ip[i];
    insert16(kv, key);
  }
#pragma unroll
  for (int j = 0; j < 16; ++j) knn[r * 16 + j] = (int)(kv[j] & 0xFFFFu);
}

// ---------------- K4: GIN aggregation: h = (1+eps)*xf + sum_k xf[idx] ----------------
__global__ __launch_bounds__(256) void k_aggr(const float* __restrict__ xf,
                                              const int* __restrict__ knn,
                                              const float* __restrict__ eps_gin,
                                              float* __restrict__ h) {
  const int tid = threadIdx.x;
  const int r = blockIdx.x * 4 + (tid >> 6);   // wave per row
  const int c = tid & 63;
  const int b = r >> 12;
  const float* xfb = xf + (size_t)b * N_ * 64;
  const float eps = eps_gin[0];
  float v = (1.f + eps) * xf[(size_t)r * 64 + c];
  const int* kn = knn + r * 16;
#pragma unroll
  for (int j = 0; j < 16; ++j) {
    int m = kn[j];                              // wave-uniform scalar load
    v += xfb[(size_t)m * 64 + c];               // coalesced 256B row read
  }
  h[(size_t)r * 64 + c] = v;
}

// ---------------- K5: h1 = h @ w1 + b1, plus BN partial sums ----------------
__global__ __launch_bounds__(256) void k_gemm1(const float* __restrict__ h,
                                               const float* __restrict__ w1,
                                               const float* __restrict__ b1,
                                               float* __restrict__ h1,
                                               float* __restrict__ bn_acc) {
  __shared__ float w[64 * 64];
  __shared__ float rs[4][64], rs2[4][64];
  const int tid = threadIdx.x;
#pragma unroll
  for (int i = 0; i < 16; ++i) w[tid + i * 256] = w1[tid + i * 256];
  __syncthreads();
  const int o = tid & 63;
  const int q = tid >> 6;
  const int r0 = blockIdx.x * 64;
  const float bias = b1[o];
  float s = 0.f, s2 = 0.f;
#pragma unroll
  for (int i = 0; i < 16; ++i) {
    int row = r0 + q + i * 4;                   // wave-uniform row
    const float* hr = h + (size_t)row * 64;
    float acc = bias;
#pragma unroll
    for (int c = 0; c < 64; ++c) acc += hr[c] * w[c * 64 + o];
    h1[(size_t)row * 64 + o] = acc;
    s += acc; s2 += acc * acc;
  }
  rs[q][o] = s; rs2[q][o] = s2;
  __syncthreads();
  if (tid < 64) {
    float ts  = rs[0][tid] + rs[1][tid] + rs[2][tid] + rs[3][tid];
    float ts2 = rs2[0][tid] + rs2[1][tid] + rs2[2][tid] + rs2[3][tid];
    atomicAdd(&bn_acc[tid], ts);
    atomicAdd(&bn_acc[64 + tid], ts2);
  }
}

// ---------------- K6: finalize BN -> per-channel scale/shift ----------------
__global__ void k_bnfin(const float* __restrict__ bn_acc,
                        const float* __restrict__ gamma,
                        const float* __restrict__ beta,
                        float* __restrict__ bn_par) {
  int o = threadIdx.x;   // 64 threads
  const float inv = 1.f / (float)ROWS_;
  float mean = bn_acc[o] * inv;
  float var  = bn_acc[64 + o] * inv - mean * mean;
  float sc = gamma[o] * rsqrtf(var + 1e-5f);
  bn_par[o] = sc;
  bn_par[64 + o] = beta[o] - mean * sc;
}

// ---------------- K7: BN apply + GELU(erf) + GEMM2 + transposed store ----------------
__global__ __launch_bounds__(256) void k_final(const float* __restrict__ h1,
                                               const float* __restrict__ bn_par,
                                               const float* __restrict__ w2,
                                               const float* __restrict__ b2,
                                               float* __restrict__ out) {
  __shared__ float w[64 * 64];
  __shared__ float hg[64 * 65];                 // padded: kills stride-64 conflicts
  const int tid = threadIdx.x;
#pragma unroll
  for (int i = 0; i < 16; ++i) w[tid + i * 256] = w2[tid + i * 256];
  const int r0 = blockIdx.x * 64;
  const int b  = r0 >> 12;
  const int n0 = r0 & (N_ - 1);
  const int o = tid & 63;
  const int q = tid >> 6;
  const float sc = bn_par[o], sh = bn_par[64 + o];
#pragma unroll
  for (int i = 0; i < 16; ++i) {
    int rl = q + i * 4;
    float v = h1[(size_t)(r0 + rl) * 64 + o] * sc + sh;
    float g = 0.5f * v * (1.f + erff(v * 0.70710678118654752f));
    hg[rl * 65 + o] = g;
  }
  __syncthreads();
  const int nl = tid & 63;
#pragma unroll
  for (int i = 0; i < 16; ++i) {
    int o2 = q + i * 4;                         // wave-uniform
    float acc = b2[o2];
#pragma unroll
    for (int oo = 0; oo < 64; ++oo) acc += hg[nl * 65 + oo] * w[oo * 64 + o2];
    out[((size_t)(b * 64 + o2)) * N_ + n0 + nl] = acc;  // coalesced over n
  }
}

extern "C" void kernel_launch(void* const* d_in, const int* in_sizes, int n_in,
                              void* d_out, int out_size, void* d_ws, size_t ws_size,
                              hipStream_t stream) {
  const float* x     = (const float*)d_in[0];
  const float* w1    = (const float*)d_in[1];
  const float* b1    = (const float*)d_in[2];
  const float* gamma = (const float*)d_in[3];
  const float* beta  = (const float*)d_in[4];
  const float* w2    = (const float*)d_in[5];
  const float* b2    = (const float*)d_in[6];
  const float* eps_g = (const float*)d_in[7];
  float* out = (float*)d_out;

  char* ws = (char*)d_ws;
  float* xf   = (float*)(ws + OFF_XF);
  float* sq   = (float*)(ws + OFF_SQ);
  u32*   kd   = (u32*)  (ws + OFF_KD);
  u16*   ki   = (u16*)  (ws + OFF_KI);
  int*   knn  = (int*)  (ws + OFF_IDX);
  float* h    = (float*)(ws + OFF_H);     // aliases kd (dead after merge)
  float* h1   = (float*)(ws + OFF_H1);    // aliases ki+knn (dead after aggr)
  float* bn_acc = (float*)(ws + OFF_BN);
  float* bn_par = (float*)(ws + OFF_BN + 512);

  k_transpose<<<512, 256, 0, stream>>>(x, xf, sq, bn_acc);
  k_knn<<<512, 256, 0, stream>>>(xf, sq, kd, ki);
  k_merge<<<ROWS_ / 256, 256, 0, stream>>>(kd, ki, knn);
  k_aggr<<<ROWS_ / 4, 256, 0, stream>>>(xf, knn, eps_g, h);
  k_gemm1<<<ROWS_ / 64, 256, 0, stream>>>(h, w1, b1, h1, bn_acc);
  k_bnfin<<<1, 64, 0, stream>>>(bn_acc, gamma, beta, bn_par);
  k_final<<<ROWS_ / 64, 256, 0, stream>>>(h1, bn_par, w2, b2, out);
}